// Round 1
// baseline (200.671 us; speedup 1.0000x reference)
//
#include <hip/hip_runtime.h>

#define BS      128
#define NF      4
#define NC      36
#define P_LO    1024
#define P_HI    16384
#define KNN     9
#define THREADS 256
#define TILE_P  256
#define NTILES  (P_HI / TILE_P)     // 64
#define LIST_OFF 64                 // ints; ws[0..35]=counts, ws[64+c*128+i]=sample ids

// ---- pre-pass: bucket samples by class into workspace ----
__global__ __launch_bounds__(128) void build_lists_kernel(
    const int* __restrict__ cls_ids, int* __restrict__ ws)
{
    __shared__ int cnt[NC];
    const int t = threadIdx.x;
    if (t < NC) cnt[t] = 0;
    __syncthreads();
    if (t < BS) {
        int c = cls_ids[t];
        int pos = atomicAdd(&cnt[c], 1);
        ws[LIST_OFF + c * BS + pos] = t;
    }
    __syncthreads();
    if (t < NC) ws[t] = cnt[t];
}

__device__ __forceinline__ void async_cp16(const void* g, void* l) {
    __builtin_amdgcn_global_load_lds(
        (const __attribute__((address_space(1))) void*)g,
        (__attribute__((address_space(3))) void*)l, 16, 0, 0);
}

// ---- main: block = (cls, f, tile); 1 position/thread; 4 samples/round ----
__global__ __launch_bounds__(THREADS, 8) void rect_up_kernel(
    const float* __restrict__ x,       // (BS, NF*P_LO)
    const int*   __restrict__ ws,      // counts + lists
    const int*   __restrict__ nbr,     // (P_HI, K)
    const float* __restrict__ wmap,    // (NC, NF, P_HI, K)
    const float* __restrict__ blo,     // (NC, NF, P_LO)
    const float* __restrict__ bhi,     // (NC, NF, P_HI)
    float*       __restrict__ out)     // (BS, NF, P_HI)
{
    // 9216 B w-tile + 9216 B idx-tile, later overlaid by 16384 B interleaved ybuf
    __shared__ __align__(16) char smem[2 * TILE_P * KNN * 4];   // 18432 B

    const int tile = blockIdx.x % NTILES;
    const int cf   = blockIdx.x / NTILES;
    const int f    = cf % NF;
    const int cls  = cf / NF;

    const int n_b = ws[cls];
    if (n_b == 0) return;              // uniform exit, before any __syncthreads

    const int tid   = threadIdx.x;
    const int tbase = tile * TILE_P;
    const int p     = tbase + tid;     // this thread's hi position

    // ---- async-stage w tile (576 f4) and idx tile (576 f4) into LDS ----
    const float4* wsrc = (const float4*)(wmap + ((size_t)(cls * NF + f) * P_HI + tbase) * KNN);
    const float4* isrc = (const float4*)(nbr + (size_t)tbase * KNN);
    float4* wdst = (float4*)smem;
    float4* idst = (float4*)(smem + TILE_P * KNN * 4);
    async_cp16(wsrc + tid,       wdst + tid);
    async_cp16(wsrc + tid + 256, wdst + tid + 256);
    async_cp16(isrc + tid,       idst + tid);
    async_cp16(isrc + tid + 256, idst + tid + 256);
    if (tid < 64) {                    // wave-aligned tail (576-512 = 64 = 1 wave)
        async_cp16(wsrc + 512 + tid, wdst + 512 + tid);
        async_cp16(isrc + 512 + tid, idst + 512 + tid);
    }

    // per-thread constants while copies are in flight
    const float* blp = blo + (size_t)(cls * NF + f) * P_LO;
    float blv0 = blp[tid];
    float blv1 = blp[tid + 256];
    float blv2 = blp[tid + 512];
    float blv3 = blp[tid + 768];
    const float bh = bhi[(size_t)(cls * NF + f) * P_HI + p];
    const int* list = ws + LIST_OFF + cls * BS;

    asm volatile("s_waitcnt vmcnt(0)" ::: "memory");
    __syncthreads();

    // ---- readback: stride-9 word reads, exactly 2 lanes/bank (conflict-free) ----
    float w[KNN]; int nb[KNN];
    {
        const float* wrow = (const float*)smem + (size_t)tid * KNN;
        const int*   irow = (const int*)(smem + TILE_P * KNN * 4) + (size_t)tid * KNN;
        #pragma unroll
        for (int k = 0; k < KNN; ++k) { w[k] = wrow[k]; nb[k] = irow[k]; }
    }
    __syncthreads();                   // staging LDS now dead -> ybuf overlays it

    float4* ybuf = (float4*)smem;      // [P_LO] float4: 4 samples interleaved

    const int R = (n_b + 3) >> 2;      // rounds of 4 samples
    for (int r = 0; r < R; ++r) {
        const int s0 = 4 * r;
        const int b0 = list[s0];
        const int b1 = list[(s0 + 1 < n_b) ? s0 + 1 : n_b - 1];
        const int b2 = list[(s0 + 2 < n_b) ? s0 + 2 : n_b - 1];
        const int b3 = list[(s0 + 3 < n_b) ? s0 + 3 : n_b - 1];
        const float* x0 = x + ((size_t)(b0 * NF + f)) * P_LO;
        const float* x1 = x + ((size_t)(b1 * NF + f)) * P_LO;
        const float* x2 = x + ((size_t)(b2 * NF + f)) * P_LO;
        const float* x3 = x + ((size_t)(b3 * NF + f)) * P_LO;

        if (r) __syncthreads();        // prev round's gathers done before rewrite

        // stage 4 bias-subtracted planes, sample-interleaved; b128 writes, no conflicts
        {
            float blv[4] = {blv0, blv1, blv2, blv3};
            #pragma unroll
            for (int m = 0; m < 4; ++m) {
                const int q = tid + (m << 8);
                const float bl = blv[m];
                float4 v;
                v.x = x0[q] - bl;
                v.y = x1[q] - bl;
                v.z = x2[q] - bl;
                v.w = x3[q] - bl;
                ybuf[q] = v;
            }
        }
        __syncthreads();

        // gather: one ds_read_b128 per neighbor feeds 4 samples' FMAs
        float a0 = 0.f, a1 = 0.f, a2 = 0.f, a3 = 0.f;
        #pragma unroll
        for (int k = 0; k < KNN; ++k) {
            const float4 yv = ybuf[nb[k]];
            a0 = fmaf(w[k], yv.x, a0);
            a1 = fmaf(w[k], yv.y, a1);
            a2 = fmaf(w[k], yv.z, a2);
            a3 = fmaf(w[k], yv.w, a3);
        }

        out[(size_t)(b0 * NF + f) * P_HI + p] = a0 + bh;
        if (s0 + 1 < n_b) out[(size_t)(b1 * NF + f) * P_HI + p] = a1 + bh;
        if (s0 + 2 < n_b) out[(size_t)(b2 * NF + f) * P_HI + p] = a2 + bh;
        if (s0 + 3 < n_b) out[(size_t)(b3 * NF + f) * P_HI + p] = a3 + bh;
    }
}

extern "C" void kernel_launch(void* const* d_in, const int* in_sizes, int n_in,
                              void* d_out, int out_size, void* d_ws, size_t ws_size,
                              hipStream_t stream) {
    const float* x    = (const float*)d_in[0];
    const int*   cls  = (const int*)d_in[1];
    const int*   nbr  = (const int*)d_in[2];
    const float* wmap = (const float*)d_in[3];
    const float* blo  = (const float*)d_in[4];
    const float* bhi  = (const float*)d_in[5];
    float*       out  = (float*)d_out;
    int*         wsl  = (int*)d_ws;   // needs (64 + 36*128)*4 = 18.7 KB

    build_lists_kernel<<<1, 128, 0, stream>>>(cls, wsl);
    rect_up_kernel<<<NC * NF * NTILES, THREADS, 0, stream>>>(
        x, wsl, nbr, wmap, blo, bhi, out);
}

// Round 2
// 158.118 us; speedup vs baseline: 1.2691x; 1.2691x over previous
//
#include <hip/hip_runtime.h>

#define BS      128
#define NF      4
#define NC      36
#define P_LO    1024
#define P_HI    16384
#define KNN     9
#define THREADS 256
#define TILE_P  256
#define NTILES  (P_HI / TILE_P)     // 64
#define LIST_OFF 64                 // ints; ws[0..35]=counts, ws[64+c*128+i]=sample ids

// ---- pre-pass: bucket samples by class into workspace ----
__global__ __launch_bounds__(128) void build_lists_kernel(
    const int* __restrict__ cls_ids, int* __restrict__ ws)
{
    __shared__ int cnt[NC];
    const int t = threadIdx.x;
    if (t < NC) cnt[t] = 0;
    __syncthreads();
    if (t < BS) {
        int c = cls_ids[t];
        int pos = atomicAdd(&cnt[c], 1);
        ws[LIST_OFF + c * BS + pos] = t;
    }
    __syncthreads();
    if (t < NC) ws[t] = cnt[t];
}

__device__ __forceinline__ void async_cp16(const void* g, void* l) {
    __builtin_amdgcn_global_load_lds(
        (const __attribute__((address_space(1))) void*)g,
        (__attribute__((address_space(3))) void*)l, 16, 0, 0);
}

// ---- main: block = (cls, f, tile); 1 position/thread; 4 samples/round ----
// NOTE: plain __launch_bounds__(256) — round 1's (256,8) floor forced VGPR=32
// and spilled the round-loop state to scratch (+126 MB HBM writes). LDS
// (18432 B) already caps residency at 8 blocks/CU; no need to force regalloc.
__global__ __launch_bounds__(THREADS) void rect_up_kernel(
    const float* __restrict__ x,       // (BS, NF*P_LO)
    const int*   __restrict__ ws,      // counts + lists
    const int*   __restrict__ nbr,     // (P_HI, K)
    const float* __restrict__ wmap,    // (NC, NF, P_HI, K)
    const float* __restrict__ blo,     // (NC, NF, P_LO)
    const float* __restrict__ bhi,     // (NC, NF, P_HI)
    float*       __restrict__ out)     // (BS, NF, P_HI)
{
    // 9216 B w-tile + 9216 B idx-tile, later overlaid by 16384 B interleaved ybuf
    __shared__ __align__(16) char smem[2 * TILE_P * KNN * 4];   // 18432 B

    const int tile = blockIdx.x % NTILES;
    const int cf   = blockIdx.x / NTILES;
    const int f    = cf % NF;
    const int cls  = cf / NF;

    const int n_b = ws[cls];
    if (n_b == 0) return;              // uniform exit, before any __syncthreads

    const int tid   = threadIdx.x;
    const int tbase = tile * TILE_P;
    const int p     = tbase + tid;     // this thread's hi position

    // ---- async-stage w tile (576 f4) and idx tile (576 f4) into LDS ----
    const float4* wsrc = (const float4*)(wmap + ((size_t)(cls * NF + f) * P_HI + tbase) * KNN);
    const float4* isrc = (const float4*)(nbr + (size_t)tbase * KNN);
    float4* wdst = (float4*)smem;
    float4* idst = (float4*)(smem + TILE_P * KNN * 4);
    async_cp16(wsrc + tid,       wdst + tid);
    async_cp16(wsrc + tid + 256, wdst + tid + 256);
    async_cp16(isrc + tid,       idst + tid);
    async_cp16(isrc + tid + 256, idst + tid + 256);
    if (tid < 64) {                    // wave-aligned tail (576-512 = 64 = 1 wave)
        async_cp16(wsrc + 512 + tid, wdst + 512 + tid);
        async_cp16(isrc + 512 + tid, idst + 512 + tid);
    }

    // per-thread constants while copies are in flight
    const float* blp = blo + (size_t)(cls * NF + f) * P_LO;
    float blv0 = blp[tid];
    float blv1 = blp[tid + 256];
    float blv2 = blp[tid + 512];
    float blv3 = blp[tid + 768];
    const float bh = bhi[(size_t)(cls * NF + f) * P_HI + p];
    const int* list = ws + LIST_OFF + cls * BS;

    asm volatile("s_waitcnt vmcnt(0)" ::: "memory");
    __syncthreads();

    // ---- readback: stride-9 word reads, exactly 2 lanes/bank (conflict-free) ----
    float w[KNN]; int nb[KNN];
    {
        const float* wrow = (const float*)smem + (size_t)tid * KNN;
        const int*   irow = (const int*)(smem + TILE_P * KNN * 4) + (size_t)tid * KNN;
        #pragma unroll
        for (int k = 0; k < KNN; ++k) { w[k] = wrow[k]; nb[k] = irow[k]; }
    }
    __syncthreads();                   // staging LDS now dead -> ybuf overlays it

    float4* ybuf = (float4*)smem;      // [P_LO] float4: 4 samples interleaved

    const int R = (n_b + 3) >> 2;      // rounds of 4 samples
    for (int r = 0; r < R; ++r) {
        const int s0 = 4 * r;
        const int b0 = list[s0];
        const int b1 = list[(s0 + 1 < n_b) ? s0 + 1 : n_b - 1];
        const int b2 = list[(s0 + 2 < n_b) ? s0 + 2 : n_b - 1];
        const int b3 = list[(s0 + 3 < n_b) ? s0 + 3 : n_b - 1];
        const float* x0 = x + ((size_t)(b0 * NF + f)) * P_LO;
        const float* x1 = x + ((size_t)(b1 * NF + f)) * P_LO;
        const float* x2 = x + ((size_t)(b2 * NF + f)) * P_LO;
        const float* x3 = x + ((size_t)(b3 * NF + f)) * P_LO;

        if (r) __syncthreads();        // prev round's gathers done before rewrite

        // stage 4 bias-subtracted planes, sample-interleaved; b128 writes, no conflicts
        {
            float blv[4] = {blv0, blv1, blv2, blv3};
            #pragma unroll
            for (int m = 0; m < 4; ++m) {
                const int q = tid + (m << 8);
                const float bl = blv[m];
                float4 v;
                v.x = x0[q] - bl;
                v.y = x1[q] - bl;
                v.z = x2[q] - bl;
                v.w = x3[q] - bl;
                ybuf[q] = v;
            }
        }
        __syncthreads();

        // gather: one ds_read_b128 per neighbor feeds 4 samples' FMAs
        float a0 = 0.f, a1 = 0.f, a2 = 0.f, a3 = 0.f;
        #pragma unroll
        for (int k = 0; k < KNN; ++k) {
            const float4 yv = ybuf[nb[k]];
            a0 = fmaf(w[k], yv.x, a0);
            a1 = fmaf(w[k], yv.y, a1);
            a2 = fmaf(w[k], yv.z, a2);
            a3 = fmaf(w[k], yv.w, a3);
        }

        out[(size_t)(b0 * NF + f) * P_HI + p] = a0 + bh;
        if (s0 + 1 < n_b) out[(size_t)(b1 * NF + f) * P_HI + p] = a1 + bh;
        if (s0 + 2 < n_b) out[(size_t)(b2 * NF + f) * P_HI + p] = a2 + bh;
        if (s0 + 3 < n_b) out[(size_t)(b3 * NF + f) * P_HI + p] = a3 + bh;
    }
}

extern "C" void kernel_launch(void* const* d_in, const int* in_sizes, int n_in,
                              void* d_out, int out_size, void* d_ws, size_t ws_size,
                              hipStream_t stream) {
    const float* x    = (const float*)d_in[0];
    const int*   cls  = (const int*)d_in[1];
    const int*   nbr  = (const int*)d_in[2];
    const float* wmap = (const float*)d_in[3];
    const float* blo  = (const float*)d_in[4];
    const float* bhi  = (const float*)d_in[5];
    float*       out  = (float*)d_out;
    int*         wsl  = (int*)d_ws;   // needs (64 + 36*128)*4 = 18.7 KB

    build_lists_kernel<<<1, 128, 0, stream>>>(cls, wsl);
    rect_up_kernel<<<NC * NF * NTILES, THREADS, 0, stream>>>(
        x, wsl, nbr, wmap, blo, bhi, out);
}